// Round 10
// baseline (788.704 us; speedup 1.0000x reference)
//
#include <hip/hip_runtime.h>

// ConvLSTM cell, MI355X. Implicit-GEMM over concat(x,h) channels, bf16 MFMA
// 32x32x16, fused in-register LSTM epilogue.
// R10: wave tile widened to 64m x 128oc (acc[2][4] = 128 AGPR) so the
// 2-blocks/CU operating point (register reality since R9) carries 16-MFMA
// clusters per merged pos: B ds_read cost per MFMA halves, A1 cover doubles
// to 256 SIMD-cyc, per-phase overhead halves. Grid 2048 (b x 8 + cb);
// cb == XCD -> each XCD L2 holds its 1.18 MB weight slice.

typedef __bf16 bf16x8 __attribute__((ext_vector_type(8)));
typedef float f32x16 __attribute__((ext_vector_type(16)));

#define PLANE_B  20736u                 // 324 positions * 64 B (18x18x32 bf16)
#define XH_BYTES (4096u * PLANE_B)      // 256 b * 16 icblk planes
#define OUT_HALF 16777216u              // B*CH*S

__device__ inline void gload_lds16(const void* g, void* l) {
    __builtin_amdgcn_global_load_lds(
        (const __attribute__((address_space(1))) void*)g,
        (__attribute__((address_space(3))) void*)l, 16, 0, 0);
}

// ---------------------------------------------------------------------------
// P1a: x,h (NCHW fp32) -> padded swizzled bf16 planes.
// addr = (p*64 + ofs) ^ ((p&7)<<4)  (bijective; same formula on read).
__global__ __launch_bounds__(256) void xh_transform(
    const float* __restrict__ x, const float* __restrict__ hh,
    unsigned char* __restrict__ xh)
{
    int blk = blockIdx.x;              // b*16 + ibk
    int b = blk >> 4, ibk = blk & 15;
    const float* src = (ibk < 8) ? (x  + ((size_t)(b*256 + ibk*32)) * 256)
                                 : (hh + ((size_t)(b*256 + (ibk-8)*32)) * 256);
    int t = threadIdx.x;               // t == spatial s
    uint32_t w[16];
#pragma unroll
    for (int i = 0; i < 16; ++i) {
        __bf16 lo = (__bf16)src[(size_t)(2*i  )*256 + t];
        __bf16 hi = (__bf16)src[(size_t)(2*i+1)*256 + t];
        w[i] = (uint32_t)__builtin_bit_cast(unsigned short, lo)
             | ((uint32_t)__builtin_bit_cast(unsigned short, hi) << 16);
    }
    unsigned char* plane = xh + (size_t)blk * PLANE_B;
    int p = ((t >> 4) + 1)*18 + (t & 15) + 1;      // interior position
    uint32_t key  = (uint32_t)(p & 7) << 4;
    uint32_t base = (uint32_t)p * 64u;
#pragma unroll
    for (int k = 0; k < 4; ++k)
        *(uint4*)(plane + ((base + 16u*k) ^ key)) =
            uint4{w[4*k], w[4*k+1], w[4*k+2], w[4*k+3]};
    // zero the 68 border positions (rows 0,17; cols 0,17)
    if (t < 68) {
        int pb;
        if      (t < 18) pb = t;                   // row 0
        else if (t < 36) pb = 17*18 + (t - 18);    // row 17
        else if (t < 52) pb = (t - 35)*18;         // rows 1..16, col 0
        else             pb = (t - 51)*18 + 17;    // rows 1..16, col 17
        uint32_t kb = (uint32_t)(pb & 7) << 4;
        uint32_t bb = (uint32_t)pb * 64u;
        uint4 z{0u,0u,0u,0u};
#pragma unroll
        for (int k = 0; k < 4; ++k)
            *(uint4*)(plane + ((bb + 16u*k) ^ kb)) = z;
    }
}

// ---------------------------------------------------------------------------
// P1b: Wx,Wh (OIHW fp32) -> Wt bf16 in A-fragment order.
__global__ __launch_bounds__(256) void w_transform(
    const float* __restrict__ Wx, const float* __restrict__ Wh,
    __bf16* __restrict__ Wt)
{
    int idx  = blockIdx.x * 256 + threadIdx.x;   // 589824 total
    int lane = idx & 63;
    int chunk = idx >> 6;                        // 9216 chunks
    int half  = chunk & 1;
    int icblk = (chunk >> 1) & 15;
    int fg    = (chunk >> 5) & 3;
    int cb    = (chunk >> 7) & 7;
    int pos   = chunk >> 10;                     // ky*3+kx
    int row = lane & 31, hl = lane >> 5;
    int gate = row & 3, ch8 = row >> 2;
    int oc  = gate*256 + cb*32 + fg*8 + ch8;
    int ic0 = icblk*32 + half*16 + hl*8;
    bf16x8 v;
#pragma unroll
    for (int j = 0; j < 8; ++j) {
        int ic = ic0 + j;
        float w = (ic < 256) ? Wx[((size_t)oc*256 + ic      )*9 + pos]
                             : Wh[((size_t)oc*256 + (ic-256))*9 + pos];
        v[j] = (__bf16)w;
    }
    *(bf16x8*)(Wt + (size_t)chunk*512 + (size_t)lane*8) = v;
}

// ---------------------------------------------------------------------------
// Main. Block = (b, cb): 256m x 128oc' (all 4 fg of one cb). 4 waves, each
// 64m x 128oc: acc[2][4] f32x16 = 128 AGPR. DMA staging; 9 merged pos x
// 16 MFMA per ibk. ibk loop unrolled by 2 (PAR literal) for A0 ping parity.
__global__ __launch_bounds__(256, 2) void convlstm_main(
    const unsigned char* __restrict__ xh, const __bf16* __restrict__ Wt,
    const float* __restrict__ bh,  const float* __restrict__ cin,
    const float* __restrict__ Wci, const float* __restrict__ Wcf,
    const float* __restrict__ Wco, float* __restrict__ out)
{
    int bid = blockIdx.x;               // b*8 + cb
    int cb  = bid & 7;
    int b   = bid >> 3;
    int tid = threadIdx.x;
    int lane = tid & 63, wv = tid >> 6;
    int l31 = lane & 31, hl = lane >> 5;

    __shared__ __align__(16) unsigned char lds[2][24576];

    // accumulators init with bias bh[oc]
    f32x16 acc[2][4];
#pragma unroll
    for (int f = 0; f < 4; ++f) {
        f32x16 v;
#pragma unroll
        for (int r = 0; r < 16; ++r) {
            int gate = r & 3, q = r >> 2;
            v[r] = bh[gate*256 + cb*32 + f*8 + 2*q + hl];
        }
        acc[0][f] = v; acc[1][f] = v;
    }

    const unsigned char* planes = xh + (size_t)b * (16u * PLANE_B);

    // stage plane 0 into buffer 0 (linear DMA; plane pre-padded+swizzled)
#pragma unroll
    for (int k = 0; k < 6; ++k)
        gload_lds16(planes + (size_t)(wv*6 + k)*1024u + (size_t)lane*16u,
                    &lds[0][(wv*6 + k)*1024 + lane*16]);

    // per-wave B-frag position bases (m = wv*64 + mf*32 + l31)
    int m0 = wv*64 + l31,       m1 = wv*64 + 32 + l31;
    int pbase0 = (m0 >> 4)*18 + (m0 & 15);
    int pbase1 = (m1 >> 4)*18 + (m1 & 15);
    const uint32_t kbase = (uint32_t)(hl*16);

    const __bf16* wlane = Wt + (size_t)lane * 8;
    auto achunk = [&](int ibk, int pos, int half, int f) -> size_t {
        return ((size_t)((pos*8 + cb)*4 + f))*32 + (size_t)(ibk*2 + half);
    };
    auto bread = [&](const unsigned char* rb, int pbase, int pos, int half) -> bf16x8 {
        int p = pbase + (pos/3)*18 + (pos%3);
        uint32_t byte = ((uint32_t)p*64u + kbase + (uint32_t)(half*32))
                        ^ (((uint32_t)(p & 7)) << 4);
        return *(const bf16x8*)(rb + byte);
    };

    __syncthreads();   // drains stage DMA + joins waves

    // A0 prologue: (ibk0, pos0, half0) x 4 fg into A[0]
    bf16x8 A[2][4];                     // [ping][f], half0 only
#pragma unroll
    for (int f = 0; f < 4; ++f)
        A[0][f] = *(const bf16x8*)(wlane + achunk(0, 0, 0, f)*512);

// One ibk body. PAR is a LITERAL 0/1: LDS buffer = PAR, ping = (pos+PAR)&1.
// pos8 writes A[PAR^1]; next body (parity PAR^1) reads pos0 from A[PAR^1]. ok
#define IBK_BODY(IBK, PAR)                                                   \
    {                                                                        \
        const int ibk = (IBK);                                               \
        if (ibk < 15) {                                                      \
            const unsigned char* np = planes + (size_t)(ibk+1) * PLANE_B;    \
            _Pragma("unroll")                                                \
            for (int k = 0; k < 6; ++k)                                      \
                gload_lds16(np + (size_t)(wv*6 + k)*1024u + (size_t)lane*16u,\
                            &lds[(PAR) ^ 1][(wv*6 + k)*1024 + lane*16]);     \
        }                                                                    \
        const unsigned char* rb = lds[(PAR)];                                \
        bf16x8 Bc[2];                                                        \
        Bc[0] = bread(rb, pbase0, 0, 0);                                     \
        Bc[1] = bread(rb, pbase1, 0, 0);                                     \
        _Pragma("unroll")                                                    \
        for (int pos = 0; pos < 9; ++pos) {                                  \
            const int ping = (pos + (PAR)) & 1;                              \
            bf16x8 A1[4];                                                    \
            _Pragma("unroll")                                                \
            for (int f = 0; f < 4; ++f)                                      \
                A1[f] = *(const bf16x8*)(wlane + achunk(ibk, pos, 1, f)*512);\
            {                                                                \
                int nib = (pos < 8) ? ibk : ((ibk < 15) ? ibk + 1 : ibk);    \
                int nps = (pos < 8) ? pos + 1 : 0;                           \
                _Pragma("unroll")                                            \
                for (int f = 0; f < 4; ++f)                                  \
                    A[ping^1][f] =                                           \
                        *(const bf16x8*)(wlane + achunk(nib, nps, 0, f)*512);\
            }                                                                \
            bf16x8 B1[2];                                                    \
            B1[0] = bread(rb, pbase0, pos, 1);                               \
            B1[1] = bread(rb, pbase1, pos, 1);                               \
            __builtin_amdgcn_s_setprio(1);                                   \
            acc[0][0] = __builtin_amdgcn_mfma_f32_32x32x16_bf16(A[ping][0], Bc[0], acc[0][0], 0, 0, 0); \
            acc[0][1] = __builtin_amdgcn_mfma_f32_32x32x16_bf16(A[ping][1], Bc[0], acc[0][1], 0, 0, 0); \
            acc[0][2] = __builtin_amdgcn_mfma_f32_32x32x16_bf16(A[ping][2], Bc[0], acc[0][2], 0, 0, 0); \
            acc[0][3] = __builtin_amdgcn_mfma_f32_32x32x16_bf16(A[ping][3], Bc[0], acc[0][3], 0, 0, 0); \
            acc[1][0] = __builtin_amdgcn_mfma_f32_32x32x16_bf16(A[ping][0], Bc[1], acc[1][0], 0, 0, 0); \
            acc[1][1] = __builtin_amdgcn_mfma_f32_32x32x16_bf16(A[ping][1], Bc[1], acc[1][1], 0, 0, 0); \
            acc[1][2] = __builtin_amdgcn_mfma_f32_32x32x16_bf16(A[ping][2], Bc[1], acc[1][2], 0, 0, 0); \
            acc[1][3] = __builtin_amdgcn_mfma_f32_32x32x16_bf16(A[ping][3], Bc[1], acc[1][3], 0, 0, 0); \
            __builtin_amdgcn_s_setprio(0);                                   \
            if (pos < 8) {                                                   \
                Bc[0] = bread(rb, pbase0, pos+1, 0);                         \
                Bc[1] = bread(rb, pbase1, pos+1, 0);                         \
            }                                                                \
            __builtin_amdgcn_s_setprio(1);                                   \
            acc[0][0] = __builtin_amdgcn_mfma_f32_32x32x16_bf16(A1[0], B1[0], acc[0][0], 0, 0, 0); \
            acc[0][1] = __builtin_amdgcn_mfma_f32_32x32x16_bf16(A1[1], B1[0], acc[0][1], 0, 0, 0); \
            acc[0][2] = __builtin_amdgcn_mfma_f32_32x32x16_bf16(A1[2], B1[0], acc[0][2], 0, 0, 0); \
            acc[0][3] = __builtin_amdgcn_mfma_f32_32x32x16_bf16(A1[3], B1[0], acc[0][3], 0, 0, 0); \
            acc[1][0] = __builtin_amdgcn_mfma_f32_32x32x16_bf16(A1[0], B1[1], acc[1][0], 0, 0, 0); \
            acc[1][1] = __builtin_amdgcn_mfma_f32_32x32x16_bf16(A1[1], B1[1], acc[1][1], 0, 0, 0); \
            acc[1][2] = __builtin_amdgcn_mfma_f32_32x32x16_bf16(A1[2], B1[1], acc[1][2], 0, 0, 0); \
            acc[1][3] = __builtin_amdgcn_mfma_f32_32x32x16_bf16(A1[3], B1[1], acc[1][3], 0, 0, 0); \
            __builtin_amdgcn_s_setprio(0);                                   \
        }                                                                    \
        __syncthreads();                                                     \
    }

    for (int ib2 = 0; ib2 < 8; ++ib2) {
        IBK_BODY(2*ib2,     0)
        IBK_BODY(2*ib2 + 1, 1)
    }
#undef IBK_BODY

    // fused LSTM epilogue. col = l31 (m), r = 4*q + gate,
    // ch = cb*32 + f*8 + 2*q + hl.
    float* outh = out;
    float* outc = out + (size_t)OUT_HALF;
    const size_t bOff = (size_t)b * (256*256);
#pragma unroll
    for (int mf = 0; mf < 2; ++mf) {
        int m = wv*64 + mf*32 + l31;
#pragma unroll
        for (int f = 0; f < 4; ++f) {
#pragma unroll
            for (int q = 0; q < 4; ++q) {
                int ch = cb*32 + f*8 + 2*q + hl;
                size_t pidx = (size_t)ch*256 + (size_t)m;
                size_t idx  = bOff + pidx;
                float cv = cin[idx];
                float pi = acc[mf][f][4*q+0];
                float pf = acc[mf][f][4*q+1];
                float pc = acc[mf][f][4*q+2];
                float po = acc[mf][f][4*q+3];
                float it = 1.f/(1.f + __expf(-(pi + Wci[pidx]*cv)));
                float ft = 1.f/(1.f + __expf(-(pf + Wcf[pidx]*cv)));
                float tc = 1.f - 2.f/(1.f + __expf(2.f*pc));
                float ct = ft*cv + it*tc;
                float ot = 1.f/(1.f + __expf(-(po + Wco[pidx]*ct)));
                float th = 1.f - 2.f/(1.f + __expf(2.f*ct));
                outh[idx] = ot*th;
                outc[idx] = ct;
            }
        }
    }
}

// ---------------------------------------------------------------------------
extern "C" void kernel_launch(void* const* d_in, const int* in_sizes, int n_in,
                              void* d_out, int out_size, void* d_ws, size_t ws_size,
                              hipStream_t stream)
{
    const float* x   = (const float*)d_in[0];
    const float* h   = (const float*)d_in[1];
    const float* c   = (const float*)d_in[2];
    const float* Wx  = (const float*)d_in[3];
    const float* Wh  = (const float*)d_in[4];
    const float* bh  = (const float*)d_in[5];
    const float* Wci = (const float*)d_in[6];
    const float* Wcf = (const float*)d_in[7];
    const float* Wco = (const float*)d_in[8];
    float* out = (float*)d_out;

    unsigned char* xh = (unsigned char*)d_ws;        // padded plane store
    __bf16* Wt = (__bf16*)(xh + (size_t)XH_BYTES + 4096); // +slack

    hipLaunchKernelGGL(xh_transform, dim3(4096), dim3(256), 0, stream, x, h, xh);
    hipLaunchKernelGGL(w_transform,  dim3(2304), dim3(256), 0, stream, Wx, Wh, Wt);
    hipLaunchKernelGGL(convlstm_main, dim3(2048), dim3(256), 0, stream,
                       xh, Wt, bh, c, Wci, Wcf, Wco, out);
}

// Round 11
// 626.367 us; speedup vs baseline: 1.2592x; 1.2592x over previous
//
#include <hip/hip_runtime.h>

// ConvLSTM cell, MI355X. Implicit-GEMM over concat(x,h) channels, bf16 MFMA
// 32x32x16, fused in-register LSTM epilogue.
// R11: R5/R9 geometry (64m x 64oc waves, 64 AGPR) + structural stall fixes:
//  - A dist-2 (A[3][2], %3 slots; 18%3==0 keeps indices static across ibks)
//  - plane DMA issued at phase 1 (3 phases of cover before first
//    post-DMA A-consume drains it on the shared vmcnt)
//  - counted barrier: s_waitcnt vmcnt(4) lgkmcnt(0) + raw s_barrier
//    (cross-ibk A prefetches stay in flight; no drain-to-0)

typedef __bf16 bf16x8 __attribute__((ext_vector_type(8)));
typedef float f32x16 __attribute__((ext_vector_type(16)));

#define PLANE_B  20736u                 // 324 positions * 64 B (18x18x32 bf16)
#define XH_BYTES (4096u * PLANE_B)      // 256 b * 16 icblk planes
#define OUT_HALF 16777216u              // B*CH*S

__device__ inline void gload_lds16(const void* g, void* l) {
    __builtin_amdgcn_global_load_lds(
        (const __attribute__((address_space(1))) void*)g,
        (__attribute__((address_space(3))) void*)l, 16, 0, 0);
}

// ---------------------------------------------------------------------------
// P1a: x,h (NCHW fp32) -> padded swizzled bf16 planes.
// addr = (p*64 + ofs) ^ ((p&7)<<4)  (bijective; same formula on read).
__global__ __launch_bounds__(256) void xh_transform(
    const float* __restrict__ x, const float* __restrict__ hh,
    unsigned char* __restrict__ xh)
{
    int blk = blockIdx.x;              // b*16 + ibk
    int b = blk >> 4, ibk = blk & 15;
    const float* src = (ibk < 8) ? (x  + ((size_t)(b*256 + ibk*32)) * 256)
                                 : (hh + ((size_t)(b*256 + (ibk-8)*32)) * 256);
    int t = threadIdx.x;               // t == spatial s
    uint32_t w[16];
#pragma unroll
    for (int i = 0; i < 16; ++i) {
        __bf16 lo = (__bf16)src[(size_t)(2*i  )*256 + t];
        __bf16 hi = (__bf16)src[(size_t)(2*i+1)*256 + t];
        w[i] = (uint32_t)__builtin_bit_cast(unsigned short, lo)
             | ((uint32_t)__builtin_bit_cast(unsigned short, hi) << 16);
    }
    unsigned char* plane = xh + (size_t)blk * PLANE_B;
    int p = ((t >> 4) + 1)*18 + (t & 15) + 1;      // interior position
    uint32_t key  = (uint32_t)(p & 7) << 4;
    uint32_t base = (uint32_t)p * 64u;
#pragma unroll
    for (int k = 0; k < 4; ++k)
        *(uint4*)(plane + ((base + 16u*k) ^ key)) =
            uint4{w[4*k], w[4*k+1], w[4*k+2], w[4*k+3]};
    // zero the 68 border positions (rows 0,17; cols 0,17)
    if (t < 68) {
        int pb;
        if      (t < 18) pb = t;                   // row 0
        else if (t < 36) pb = 17*18 + (t - 18);    // row 17
        else if (t < 52) pb = (t - 35)*18;         // rows 1..16, col 0
        else             pb = (t - 51)*18 + 17;    // rows 1..16, col 17
        uint32_t kb = (uint32_t)(pb & 7) << 4;
        uint32_t bb = (uint32_t)pb * 64u;
        uint4 z{0u,0u,0u,0u};
#pragma unroll
        for (int k = 0; k < 4; ++k)
            *(uint4*)(plane + ((bb + 16u*k) ^ kb)) = z;
    }
}

// ---------------------------------------------------------------------------
// P1b: Wx,Wh (OIHW fp32) -> Wt bf16 in A-fragment order.
__global__ __launch_bounds__(256) void w_transform(
    const float* __restrict__ Wx, const float* __restrict__ Wh,
    __bf16* __restrict__ Wt)
{
    int idx  = blockIdx.x * 256 + threadIdx.x;   // 589824 total
    int lane = idx & 63;
    int chunk = idx >> 6;                        // 9216 chunks
    int half  = chunk & 1;
    int icblk = (chunk >> 1) & 15;
    int fg    = (chunk >> 5) & 3;
    int cb    = (chunk >> 7) & 7;
    int pos   = chunk >> 10;                     // ky*3+kx
    int row = lane & 31, hl = lane >> 5;
    int gate = row & 3, ch8 = row >> 2;
    int oc  = gate*256 + cb*32 + fg*8 + ch8;
    int ic0 = icblk*32 + half*16 + hl*8;
    bf16x8 v;
#pragma unroll
    for (int j = 0; j < 8; ++j) {
        int ic = ic0 + j;
        float w = (ic < 256) ? Wx[((size_t)oc*256 + ic      )*9 + pos]
                             : Wh[((size_t)oc*256 + (ic-256))*9 + pos];
        v[j] = (__bf16)w;
    }
    *(bf16x8*)(Wt + (size_t)chunk*512 + (size_t)lane*8) = v;
}

// ---------------------------------------------------------------------------
// Main. Block = (b, nh, cb): 256m x 64oc'. 4 waves, each 64m x 64oc:
// acc[2][2] f32x16 = 64 AGPR. 18 phases/ibk; A dist-2 (%3 slots), B dist-1
// ping-pong, DMA at phase 1, counted-vmcnt barrier.
__global__ __launch_bounds__(256, 2) void convlstm_main(
    const unsigned char* __restrict__ xh, const __bf16* __restrict__ Wt,
    const float* __restrict__ bh,  const float* __restrict__ cin,
    const float* __restrict__ Wci, const float* __restrict__ Wcf,
    const float* __restrict__ Wco, float* __restrict__ out)
{
    int bid = blockIdx.x;               // b*16 + nh*8 + cb
    int cb  = bid & 7;
    int nh  = (bid >> 3) & 1;
    int b   = bid >> 4;
    int tid = threadIdx.x;
    int lane = tid & 63, wv = tid >> 6;
    int l31 = lane & 31, hl = lane >> 5;

    __shared__ __align__(16) unsigned char lds[2][24576];

    // accumulators init with bias bh[oc]
    f32x16 acc[2][2];
#pragma unroll
    for (int f = 0; f < 2; ++f) {
        int fg = nh*2 + f;
        f32x16 v;
#pragma unroll
        for (int r = 0; r < 16; ++r) {
            int gate = r & 3, q = r >> 2;
            v[r] = bh[gate*256 + cb*32 + fg*8 + 2*q + hl];
        }
        acc[0][f] = v; acc[1][f] = v;
    }

    const unsigned char* planes = xh + (size_t)b * (16u * PLANE_B);

    // stage plane 0 into buffer 0 (linear DMA; plane pre-padded+swizzled)
#pragma unroll
    for (int k = 0; k < 6; ++k)
        gload_lds16(planes + (size_t)(wv*6 + k)*1024u + (size_t)lane*16u,
                    &lds[0][(wv*6 + k)*1024 + lane*16]);

    // per-wave B-frag position bases (m = wv*64 + mf*32 + l31)
    int m0 = wv*64 + l31,       m1 = wv*64 + 32 + l31;
    int pbase0 = (m0 >> 4)*18 + (m0 & 15);
    int pbase1 = (m1 >> 4)*18 + (m1 & 15);
    const uint32_t kbase = (uint32_t)(hl*16);

    const __bf16* wlane = Wt + (size_t)lane * 8;
    auto achunk = [&](int ibk, int ph, int f) -> size_t {
        int pos = ph >> 1, half = ph & 1, fg = nh*2 + f;
        return ((size_t)((pos*8 + cb)*4 + fg))*32 + (size_t)(ibk*2 + half);
    };
    auto bread = [&](const unsigned char* rb, int pbase, int ph) -> bf16x8 {
        int pos = ph >> 1, half = ph & 1;
        int p = pbase + (pos/3)*18 + (pos%3);
        uint32_t byte = ((uint32_t)p*64u + kbase + (uint32_t)(half*32))
                        ^ (((uint32_t)(p & 7)) << 4);
        return *(const bf16x8*)(rb + byte);
    };

    // A prologue: (ibk0, ph0)->slot0, (ibk0, ph1)->slot1
    bf16x8 A[3][2];
#pragma unroll
    for (int f = 0; f < 2; ++f) {
        A[0][f] = *(const bf16x8*)(wlane + achunk(0, 0, f)*512);
        A[1][f] = *(const bf16x8*)(wlane + achunk(0, 1, f)*512);
    }

    __syncthreads();   // prologue: full drain once (DMA + joins waves)

    for (int ibk = 0; ibk < 16; ++ibk) {
        const unsigned char* rb = lds[ibk & 1];

        // B pipeline restart: phase 0 reads (buffer valid only after barrier)
        bf16x8 Bb[2][2];
        Bb[0][0] = bread(rb, pbase0, 0);
        Bb[0][1] = bread(rb, pbase1, 0);

#pragma unroll
        for (int p = 0; p < 18; ++p) {
            // A prefetch distance 2 into slot (p+2)%3 (static: p literal).
            // Crosses the ibk boundary at p=16,17 (18%3==0 keeps slots
            // consistent). At ibk 15 the cross-prefetch re-reads ibk 15
            // (dummy, never consumed).
            {
                int tp  = p + 2;
                int nib = (tp < 18) ? ibk : ((ibk < 15) ? ibk + 1 : 15);
                int nph = (tp < 18) ? tp : tp - 18;
#pragma unroll
                for (int f = 0; f < 2; ++f)
                    A[(p+2)%3][f] =
                        *(const bf16x8*)(wlane + achunk(nib, nph, f)*512);
            }
            // plane DMA issued at phase 1: phases 2,3 consume pre-DMA A
            // loads, so the first post-DMA A-consume (phase 4's wait on
            // phase-2-issued A) gives the DMA ~3 phases of cover.
            if (p == 1 && ibk < 15) {
                const unsigned char* np = planes + (size_t)(ibk+1) * PLANE_B;
#pragma unroll
                for (int k = 0; k < 6; ++k)
                    gload_lds16(np + (size_t)(wv*6 + k)*1024u
                                   + (size_t)lane*16u,
                                &lds[(ibk & 1) ^ 1][(wv*6 + k)*1024 + lane*16]);
            }
            // B prefetch distance 1
            if (p < 17) {
                Bb[(p+1)&1][0] = bread(rb, pbase0, p+1);
                Bb[(p+1)&1][1] = bread(rb, pbase1, p+1);
            }
            __builtin_amdgcn_s_setprio(1);
            acc[0][0] = __builtin_amdgcn_mfma_f32_32x32x16_bf16(A[p%3][0], Bb[p&1][0], acc[0][0], 0, 0, 0);
            acc[0][1] = __builtin_amdgcn_mfma_f32_32x32x16_bf16(A[p%3][1], Bb[p&1][0], acc[0][1], 0, 0, 0);
            acc[1][0] = __builtin_amdgcn_mfma_f32_32x32x16_bf16(A[p%3][0], Bb[p&1][1], acc[1][0], 0, 0, 0);
            acc[1][1] = __builtin_amdgcn_mfma_f32_32x32x16_bf16(A[p%3][1], Bb[p&1][1], acc[1][1], 0, 0, 0);
            __builtin_amdgcn_s_setprio(0);
        }

        // Counted barrier (T4): allow the 4 newest vmem ops (phase 16/17
        // cross-ibk A prefetches) to stay in flight; everything older —
        // including this ibk's DMA — must be complete. lgkmcnt(0) orders
        // outstanding ds_reads vs next ibk's DMA overwrite.
        asm volatile("s_waitcnt vmcnt(4) lgkmcnt(0)" ::: "memory");
        __builtin_amdgcn_s_barrier();
        __builtin_amdgcn_sched_barrier(0);
    }

    // fused LSTM epilogue. col = l31 (m), r = 4*q + gate,
    // ch = cb*32 + fg*8 + 2*q + hl.
    float* outh = out;
    float* outc = out + (size_t)OUT_HALF;
    const size_t bOff = (size_t)b * (256*256);
#pragma unroll
    for (int mf = 0; mf < 2; ++mf) {
        int m = wv*64 + mf*32 + l31;
#pragma unroll
        for (int f = 0; f < 2; ++f) {
            int fg = nh*2 + f;
#pragma unroll
            for (int q = 0; q < 4; ++q) {
                int ch = cb*32 + fg*8 + 2*q + hl;
                size_t pidx = (size_t)ch*256 + (size_t)m;
                size_t idx  = bOff + pidx;
                float cv = cin[idx];
                float pi = acc[mf][f][4*q+0];
                float pf = acc[mf][f][4*q+1];
                float pc = acc[mf][f][4*q+2];
                float po = acc[mf][f][4*q+3];
                float it = 1.f/(1.f + __expf(-(pi + Wci[pidx]*cv)));
                float ft = 1.f/(1.f + __expf(-(pf + Wcf[pidx]*cv)));
                float tc = 1.f - 2.f/(1.f + __expf(2.f*pc));
                float ct = ft*cv + it*tc;
                float ot = 1.f/(1.f + __expf(-(po + Wco[pidx]*ct)));
                float th = 1.f - 2.f/(1.f + __expf(2.f*ct));
                outh[idx] = ot*th;
                outc[idx] = ct;
            }
        }
    }
}

// ---------------------------------------------------------------------------
extern "C" void kernel_launch(void* const* d_in, const int* in_sizes, int n_in,
                              void* d_out, int out_size, void* d_ws, size_t ws_size,
                              hipStream_t stream)
{
    const float* x   = (const float*)d_in[0];
    const float* h   = (const float*)d_in[1];
    const float* c   = (const float*)d_in[2];
    const float* Wx  = (const float*)d_in[3];
    const float* Wh  = (const float*)d_in[4];
    const float* bh  = (const float*)d_in[5];
    const float* Wci = (const float*)d_in[6];
    const float* Wcf = (const float*)d_in[7];
    const float* Wco = (const float*)d_in[8];
    float* out = (float*)d_out;

    unsigned char* xh = (unsigned char*)d_ws;        // padded plane store
    __bf16* Wt = (__bf16*)(xh + (size_t)XH_BYTES + 4096); // +slack

    hipLaunchKernelGGL(xh_transform, dim3(4096), dim3(256), 0, stream, x, h, xh);
    hipLaunchKernelGGL(w_transform,  dim3(2304), dim3(256), 0, stream, Wx, Wh, Wt);
    hipLaunchKernelGGL(convlstm_main, dim3(4096), dim3(256), 0, stream,
                       xh, Wt, bh, c, Wci, Wcf, Wco, out);
}